// Round 7
// baseline (345.229 us; speedup 1.0000x reference)
//
#include <hip/hip_runtime.h>
#include <math.h>

__device__ __forceinline__ float f4c(const float4& v, int t) {
  return t == 0 ? v.x : t == 1 ? v.y : t == 2 ? v.z : v.w;
}

// ---------------- CSR build ----------------
__global__ void histo_kernel(const int* __restrict__ ei, int E, int N,
                             int* __restrict__ counts) {
  int e = blockIdx.x * blockDim.x + threadIdx.x;
  int etot = E + N;
  if (e >= etot) return;
  int d = (e < E) ? ei[E + e] : (e - E);
  atomicAdd(&counts[d], 1);
}

__global__ void scan1_kernel(const int* __restrict__ counts, int* __restrict__ excl,
                             int* __restrict__ bsums, int N) {
  __shared__ int sm[256];
  int t = threadIdx.x;
  int i = blockIdx.x * 256 + t;
  int v = (i < N) ? counts[i] : 0;
  sm[t] = v;
  __syncthreads();
#pragma unroll
  for (int off = 1; off < 256; off <<= 1) {
    int add = (t >= off) ? sm[t - off] : 0;
    __syncthreads();
    sm[t] += add;
    __syncthreads();
  }
  if (i < N) excl[i] = sm[t] - v;
  if (t == 255) bsums[blockIdx.x] = sm[255];
}

__global__ void scan2_kernel(int* __restrict__ bsums, int nb) {
  __shared__ int sm[256];
  int t = threadIdx.x;
  int v = (t < nb) ? bsums[t] : 0;
  sm[t] = v;
  __syncthreads();
#pragma unroll
  for (int off = 1; off < 256; off <<= 1) {
    int add = (t >= off) ? sm[t - off] : 0;
    __syncthreads();
    sm[t] += add;
    __syncthreads();
  }
  if (t < nb) bsums[t] = sm[t] - v;  // exclusive
}

__global__ void scan3_kernel(const int* __restrict__ excl, const int* __restrict__ bsums,
                             int* __restrict__ rowptr, int* __restrict__ cursor,
                             int N, int etot) {
  int i = blockIdx.x * 256 + threadIdx.x;
  if (i < N) {
    int v = excl[i] + bsums[i >> 8];
    rowptr[i] = v;
    cursor[i] = v;
  }
  if (i == N) rowptr[N] = etot;
}

__global__ void scatter_kernel(const int* __restrict__ ei, int E, int N,
                               int* __restrict__ cursor, int* __restrict__ csr_src) {
  int e = blockIdx.x * blockDim.x + threadIdx.x;
  int etot = E + N;
  if (e >= etot) return;
  int s, d;
  if (e < E) { s = ei[e]; d = ei[E + e]; } else { s = e - E; d = e - E; }
  int pos = atomicAdd(&cursor[d], 1);
  csr_src[pos] = s;
}

// ---------------- degree counting-sort, LDS-aggregated ----------------
__global__ void deghist_kernel(const int* __restrict__ rowptr, int N,
                               int* __restrict__ dhist) {
  __shared__ int lh[1024];
  int t = threadIdx.x;
  for (int i = t; i < 1024; i += 256) lh[i] = 0;
  __syncthreads();
  int i = blockIdx.x * 256 + t;
  if (i < N) {
    int d = rowptr[i + 1] - rowptr[i];
    int key = d < 1023 ? d : 1023;
    atomicAdd(&lh[key], 1);
  }
  __syncthreads();
  for (int bin = t; bin < 1024; bin += 256) {
    int c = lh[bin];
    if (c) atomicAdd(&dhist[bin], c);
  }
}

__global__ void degscan_kernel(int* __restrict__ dhist) {  // 1 block x 1024
  __shared__ int sm[1024];
  int t = threadIdx.x;
  int v = dhist[t];
  sm[t] = v;
  __syncthreads();
#pragma unroll
  for (int off = 1; off < 1024; off <<= 1) {
    int add = (t >= off) ? sm[t - off] : 0;
    __syncthreads();
    sm[t] += add;
    __syncthreads();
  }
  dhist[t] = sm[t] - v;  // exclusive
}

__global__ void degscatter_kernel(const int* __restrict__ rowptr, int N,
                                  int* __restrict__ dhist, int* __restrict__ perm) {
  __shared__ int lc[1024];
  __shared__ int lb[1024];
  int t = threadIdx.x;
  for (int i = t; i < 1024; i += 256) lc[i] = 0;
  __syncthreads();
  int i = blockIdx.x * 256 + t;
  int key = 0, lr = 0;
  if (i < N) {
    int d = rowptr[i + 1] - rowptr[i];
    key = d < 1023 ? d : 1023;
    lr = atomicAdd(&lc[key], 1);
  }
  __syncthreads();
  for (int bin = t; bin < 1024; bin += 256) {
    int c = lc[bin];
    if (c) lb[bin] = atomicAdd(&dhist[bin], c);
  }
  __syncthreads();
  if (i < N) perm[lb[key] + lr] = i;
}

// ---------------- GEMM: H = X(N x 128) @ W(128 x COLS) + hl/hr epilogue -------
template <int COLS>
__global__ __launch_bounds__(256) void gemm_kernel(
    const float* __restrict__ X, const float* __restrict__ W,
    const float* __restrict__ al, const float* __restrict__ ar,
    float* __restrict__ H, float* __restrict__ hl, float* __restrict__ hr, int N) {
  constexpr int KC = 64;
  constexpr int XS = KC + 4;  // 2-way bank alias (free)
  __shared__ float Ws[KC * COLS];
  __shared__ float Xs[64 * XS];
  const int tid = threadIdx.x;
  const int tx = tid & 15, ty = tid >> 4;
  const int r0 = blockIdx.x * 64;

  float acc[4][2][4];
#pragma unroll
  for (int i = 0; i < 4; ++i)
#pragma unroll
    for (int h = 0; h < 2; ++h)
#pragma unroll
      for (int j = 0; j < 4; ++j) acc[i][h][j] = 0.f;

  for (int k0 = 0; k0 < 128; k0 += KC) {
    __syncthreads();
    constexpr int WQ = KC * COLS / 4;
    const float4* wg = (const float4*)(W + k0 * COLS);
#pragma unroll
    for (int i = tid; i < WQ; i += 256) ((float4*)Ws)[i] = wg[i];
#pragma unroll
    for (int i = tid; i < 64 * KC / 4; i += 256) {
      int row = i >> 4;
      int kq = i & 15;
      int gr = r0 + row;
      if (gr > N - 1) gr = N - 1;
      float4 v = *(const float4*)(X + (size_t)gr * 128 + k0 + kq * 4);
      *(float4*)(&Xs[row * XS + kq * 4]) = v;
    }
    __syncthreads();
#pragma unroll
    for (int kk0 = 0; kk0 < KC; kk0 += 4) {
      float4 xv[4];
#pragma unroll
      for (int i = 0; i < 4; ++i)
        xv[i] = *(const float4*)(&Xs[(ty * 4 + i) * XS + kk0]);
#pragma unroll
      for (int t = 0; t < 4; ++t) {
        float4 w0 = *(const float4*)(&Ws[(kk0 + t) * COLS + tx * 4]);
        float4 w1;
        if constexpr (COLS == 128) w1 = *(const float4*)(&Ws[(kk0 + t) * COLS + 64 + tx * 4]);
#pragma unroll
        for (int i = 0; i < 4; ++i) {
          float xk = f4c(xv[i], t);
          acc[i][0][0] = fmaf(xk, w0.x, acc[i][0][0]);
          acc[i][0][1] = fmaf(xk, w0.y, acc[i][0][1]);
          acc[i][0][2] = fmaf(xk, w0.z, acc[i][0][2]);
          acc[i][0][3] = fmaf(xk, w0.w, acc[i][0][3]);
          if constexpr (COLS == 128) {
            acc[i][1][0] = fmaf(xk, w1.x, acc[i][1][0]);
            acc[i][1][1] = fmaf(xk, w1.y, acc[i][1][1]);
            acc[i][1][2] = fmaf(xk, w1.z, acc[i][1][2]);
            acc[i][1][3] = fmaf(xk, w1.w, acc[i][1][3]);
          }
        }
      }
    }
  }

  float4 alv0 = *(const float4*)(al + tx * 4);
  float4 arv0 = *(const float4*)(ar + tx * 4);
  float4 alv1, arv1;
  if constexpr (COLS == 128) {
    alv1 = *(const float4*)(al + 64 + tx * 4);
    arv1 = *(const float4*)(ar + 64 + tx * 4);
  }
#pragma unroll
  for (int i = 0; i < 4; ++i) {
    int r = r0 + ty * 4 + i;
    bool ok = r < N;
    float4 o0 = make_float4(acc[i][0][0], acc[i][0][1], acc[i][0][2], acc[i][0][3]);
    float pl = o0.x * alv0.x + o0.y * alv0.y + o0.z * alv0.z + o0.w * alv0.w;
    float pr = o0.x * arv0.x + o0.y * arv0.y + o0.z * arv0.z + o0.w * arv0.w;
    if (ok) *(float4*)(&H[(size_t)r * COLS + tx * 4]) = o0;
    if constexpr (COLS == 128) {
      float4 o1 = make_float4(acc[i][1][0], acc[i][1][1], acc[i][1][2], acc[i][1][3]);
      pl += o1.x * alv1.x + o1.y * alv1.y + o1.z * alv1.z + o1.w * alv1.w;
      pr += o1.x * arv1.x + o1.y * arv1.y + o1.z * arv1.z + o1.w * arv1.w;
      if (ok) *(float4*)(&H[(size_t)r * COLS + 64 + tx * 4]) = o1;
    }
#pragma unroll
    for (int off = 1; off < 16; off <<= 1) {
      pl += __shfl_xor(pl, off);
      pr += __shfl_xor(pr, off);
    }
    if (ok && tx == 0) {
      hl[r] = pl;
      hr[r] = pr;
    }
  }
}

// ---------------- per-node attention + aggregation ----------------
// Wave = 8 groups x 8 lanes; each GROUP owns one node. Octile-strided
// schedule: group g of wave-chunk c takes sorted node (g*C + c), C = ceil(N/8).
// Every wave holds one node from each degree octile -> per-wave work and
// duration are near-uniform across ALL waves, so occupancy stays flat
// (no light-wave retirement holes, no heavy-straggler tail).
// csr_src prefetched 2 ahead; H row + hl prefetched 1 ahead.
template <int COLS, bool LAST>
__global__ __launch_bounds__(256) void node_kernel(
    const float* __restrict__ H, const float* __restrict__ hl,
    const float* __restrict__ hr, const int* __restrict__ rowptr,
    const int* __restrict__ csr_src, const int* __restrict__ perm,
    const float* __restrict__ b, float* __restrict__ OUT, int N) {
  constexpr int GS = 8;
  constexpr int EPL = COLS / GS;  // 16 (COLS=128) or 8 (COLS=64)
  constexpr int NF4 = EPL / 4;
  const int lane = threadIdx.x & 63;
  const int g = lane >> 3, l = lane & 7;
  const int C = (N + GS - 1) / GS;                       // nodes per group-slot
  const int c = blockIdx.x * 4 + (threadIdx.x >> 6);     // wave-chunk id
  const int idx = g * C + c;
  const bool active = (c < C) && (idx < N);
  const int node = active ? perm[idx] : 0;

  float hi[EPL];
  {
    const float* hp = H + (size_t)node * COLS + l * EPL;
#pragma unroll
    for (int q = 0; q < NF4; ++q) *(float4*)&hi[q * 4] = *(const float4*)(hp + q * 4);
  }
  const float hri = hr[node];
  int e = active ? rowptr[node] : 0;
  const int end = active ? rowptr[node + 1] : 0;

  float m = -INFINITY, sumw = 0.f;
  float acc[EPL];
#pragma unroll
  for (int j = 0; j < EPL; ++j) acc[j] = 0.f;

  float hls;
  float hv[EPL];
  int sB = 0;
  if (e < end) {
    int s0 = csr_src[e];
    hls = hl[s0];
    const float* hp = H + (size_t)s0 * COLS + l * EPL;
#pragma unroll
    for (int q = 0; q < NF4; ++q) *(float4*)&hv[q * 4] = *(const float4*)(hp + q * 4);
    if (e + 1 < end) sB = csr_src[e + 1];  // index for e+1 already resident
  }

  for (; e < end; ++e) {
    float ch[EPL];
#pragma unroll
    for (int j = 0; j < EPL; ++j) ch[j] = hv[j];
    const float chl = hls;
    // issue next-edge gather immediately (index already in register)
    if (e + 1 < end) {
      hls = hl[sB];
      const float* hp = H + (size_t)sB * COLS + l * EPL;
#pragma unroll
      for (int q = 0; q < NF4; ++q) *(float4*)&hv[q * 4] = *(const float4*)(hp + q * 4);
    }
    int sC = (e + 2 < end) ? csr_src[e + 2] : 0;  // overlaps with compute below
    float d = 0.f;
#pragma unroll
    for (int j = 0; j < EPL; ++j) d = fmaf(hi[j], ch[j], d);
    d += __shfl_xor(d, 1);
    d += __shfl_xor(d, 2);
    d += __shfl_xor(d, 4);
    float gate = 1.f / (1.f + __expf(-d));
    float a = (chl + hri) * gate;
    a = (a >= 0.f) ? a : 0.2f * a;
    float dm = a - m;
    if (dm > 30.f) {             // first edge (m=-inf) or rare big jump
      float sc = __expf(-dm);    // exp(m - a); first edge: exp(-inf) = 0
      sumw *= sc;
#pragma unroll
      for (int j = 0; j < EPL; ++j) acc[j] *= sc;
      m = a;
      dm = 0.f;
    }
    float w = __expf(dm);        // bounded by e^30 - f32 safe
    sumw += w;
#pragma unroll
    for (int j = 0; j < EPL; ++j) acc[j] = fmaf(w, ch[j], acc[j]);
    sB = sC;
  }

  if (!active) return;
  const float inv = 1.f / (sumw + 1e-16f);
  float o[EPL];
  const float* bp = b + l * EPL;
#pragma unroll
  for (int j = 0; j < EPL; ++j) o[j] = fmaxf(acc[j] * inv + bp[j], 0.f);

  if constexpr (LAST) {
    // COLS == 64, EPL == 8: log_softmax over the group's 64 values
    float mx = o[0];
#pragma unroll
    for (int j = 1; j < EPL; ++j) mx = fmaxf(mx, o[j]);
    mx = fmaxf(mx, __shfl_xor(mx, 1));
    mx = fmaxf(mx, __shfl_xor(mx, 2));
    mx = fmaxf(mx, __shfl_xor(mx, 4));
    float es = 0.f;
#pragma unroll
    for (int j = 0; j < EPL; ++j) es += __expf(o[j] - mx);
    es += __shfl_xor(es, 1);
    es += __shfl_xor(es, 2);
    es += __shfl_xor(es, 4);
    float ls = logf(es);
#pragma unroll
    for (int q = 0; q < NF4; ++q) {
      float4 ov = make_float4(o[q * 4 + 0] - mx - ls, o[q * 4 + 1] - mx - ls,
                              o[q * 4 + 2] - mx - ls, o[q * 4 + 3] - mx - ls);
      *(float4*)(&OUT[(size_t)node * COLS + l * EPL + q * 4]) = ov;
    }
  } else {
#pragma unroll
    for (int q = 0; q < NF4; ++q) {
      float4 ov = make_float4(o[q * 4 + 0], o[q * 4 + 1], o[q * 4 + 2], o[q * 4 + 3]);
      *(float4*)(&OUT[(size_t)node * COLS + l * EPL + q * 4]) = ov;
    }
  }
}

// ---------------- launch ----------------
extern "C" void kernel_launch(void* const* d_in, const int* in_sizes, int n_in,
                              void* d_out, int out_size, void* d_ws, size_t ws_size,
                              hipStream_t stream) {
  const float* x = (const float*)d_in[0];
  const int* ei = (const int*)d_in[1];
  const float* W0 = (const float*)d_in[2];
  const float* al0 = (const float*)d_in[3];
  const float* ar0 = (const float*)d_in[4];
  const float* b0 = (const float*)d_in[5];
  const float* W1 = (const float*)d_in[6];
  const float* al1 = (const float*)d_in[7];
  const float* ar1 = (const float*)d_in[8];
  const float* b1 = (const float*)d_in[9];
  const float* W2 = (const float*)d_in[10];
  const float* al2 = (const float*)d_in[11];
  const float* ar2 = (const float*)d_in[12];
  const float* b2 = (const float*)d_in[13];

  const int N = in_sizes[0] / 128;  // 50000
  const int E = in_sizes[1] / 2;    // 640000
  const int ETOT = E + N;

  char* p = (char*)d_ws;
  auto carve = [&](size_t bytes) {
    void* r = (void*)p;
    p += (bytes + 255) & ~(size_t)255;
    return r;
  };
  float* hA = (float*)carve((size_t)N * 128 * sizeof(float));
  float* hB = (float*)carve((size_t)N * 128 * sizeof(float));
  float* hl = (float*)carve((size_t)N * sizeof(float));
  float* hr = (float*)carve((size_t)N * sizeof(float));
  int* counts = (int*)carve((size_t)N * sizeof(int));
  int* excl = (int*)carve((size_t)N * sizeof(int));
  int* bsums = (int*)carve(1024 * sizeof(int));
  int* rowptr = (int*)carve((size_t)(N + 1) * sizeof(int));
  int* cursor = (int*)carve((size_t)(N + 1) * sizeof(int));
  int* csr_src = (int*)carve((size_t)ETOT * sizeof(int));
  int* dhist = (int*)carve(1024 * sizeof(int));
  int* perm = (int*)carve((size_t)N * sizeof(int));

  // ---- CSR build ----
  hipMemsetAsync(counts, 0, (size_t)N * sizeof(int), stream);
  hipMemsetAsync(dhist, 0, 1024 * sizeof(int), stream);
  {
    int nb = (ETOT + 255) / 256;
    histo_kernel<<<nb, 256, 0, stream>>>(ei, E, N, counts);
  }
  int nbs = (N + 255) / 256;
  scan1_kernel<<<nbs, 256, 0, stream>>>(counts, excl, bsums, N);
  scan2_kernel<<<1, 256, 0, stream>>>(bsums, nbs);
  scan3_kernel<<<(N + 256) / 256 + 1, 256, 0, stream>>>(excl, bsums, rowptr, cursor, N, ETOT);
  {
    int nb = (ETOT + 255) / 256;
    scatter_kernel<<<nb, 256, 0, stream>>>(ei, E, N, cursor, csr_src);
  }
  // ---- degree sort (LDS-aggregated counting sort) ----
  deghist_kernel<<<nbs, 256, 0, stream>>>(rowptr, N, dhist);
  degscan_kernel<<<1, 1024, 0, stream>>>(dhist);
  degscatter_kernel<<<nbs, 256, 0, stream>>>(rowptr, N, dhist, perm);

  const int gemm_grid = (N + 63) / 64;
  const int C = (N + 7) / 8;          // nodes per group-slot
  const int node_grid = (C + 3) / 4;  // 4 waves per block

  gemm_kernel<128><<<gemm_grid, 256, 0, stream>>>(x, W0, al0, ar0, hA, hl, hr, N);
  node_kernel<128, false><<<node_grid, 256, 0, stream>>>(hA, hl, hr, rowptr, csr_src, perm, b0, hB, N);

  gemm_kernel<128><<<gemm_grid, 256, 0, stream>>>(hB, W1, al1, ar1, hA, hl, hr, N);
  node_kernel<128, false><<<node_grid, 256, 0, stream>>>(hA, hl, hr, rowptr, csr_src, perm, b1, hB, N);

  gemm_kernel<64><<<gemm_grid, 256, 0, stream>>>(hB, W2, al2, ar2, hA, hl, hr, N);
  node_kernel<64, true><<<node_grid, 256, 0, stream>>>(hA, hl, hr, rowptr, csr_src, perm, b2,
                                                       (float*)d_out, N);
}

// Round 8
// 302.629 us; speedup vs baseline: 1.1408x; 1.1408x over previous
//
#include <hip/hip_runtime.h>
#include <math.h>

__device__ __forceinline__ float f4c(const float4& v, int t) {
  return t == 0 ? v.x : t == 1 ? v.y : t == 2 ? v.z : v.w;
}
// bf16 helpers: H is stored as bf16 (2B), unpacked from uint (2 elems/uint)
__device__ __forceinline__ float bflo(unsigned int u) {
  union { unsigned int i; float f; } v; v.i = u << 16; return v.f;
}
__device__ __forceinline__ float bfhi(unsigned int u) {
  union { unsigned int i; float f; } v; v.i = u & 0xFFFF0000u; return v.f;
}
__device__ __forceinline__ unsigned int f2bf_pack(float a, float b) {  // RNE
  union { float f; unsigned int i; } x, y; x.f = a; y.f = b;
  unsigned int xa = x.i + 0x7FFFu + ((x.i >> 16) & 1u);
  unsigned int yb = y.i + 0x7FFFu + ((y.i >> 16) & 1u);
  return (xa >> 16) | (yb & 0xFFFF0000u);
}

// ---------------- CSR build ----------------
__global__ void histo_kernel(const int* __restrict__ ei, int E, int N,
                             int* __restrict__ counts) {
  int e = blockIdx.x * blockDim.x + threadIdx.x;
  int etot = E + N;
  if (e >= etot) return;
  int d = (e < E) ? ei[E + e] : (e - E);
  atomicAdd(&counts[d], 1);
}

__global__ void scan1_kernel(const int* __restrict__ counts, int* __restrict__ excl,
                             int* __restrict__ bsums, int N) {
  __shared__ int sm[256];
  int t = threadIdx.x;
  int i = blockIdx.x * 256 + t;
  int v = (i < N) ? counts[i] : 0;
  sm[t] = v;
  __syncthreads();
#pragma unroll
  for (int off = 1; off < 256; off <<= 1) {
    int add = (t >= off) ? sm[t - off] : 0;
    __syncthreads();
    sm[t] += add;
    __syncthreads();
  }
  if (i < N) excl[i] = sm[t] - v;
  if (t == 255) bsums[blockIdx.x] = sm[255];
}

__global__ void scan2_kernel(int* __restrict__ bsums, int nb) {
  __shared__ int sm[256];
  int t = threadIdx.x;
  int v = (t < nb) ? bsums[t] : 0;
  sm[t] = v;
  __syncthreads();
#pragma unroll
  for (int off = 1; off < 256; off <<= 1) {
    int add = (t >= off) ? sm[t - off] : 0;
    __syncthreads();
    sm[t] += add;
    __syncthreads();
  }
  if (t < nb) bsums[t] = sm[t] - v;  // exclusive
}

__global__ void scan3_kernel(const int* __restrict__ excl, const int* __restrict__ bsums,
                             int* __restrict__ rowptr, int* __restrict__ cursor,
                             int N, int etot) {
  int i = blockIdx.x * 256 + threadIdx.x;
  if (i < N) {
    int v = excl[i] + bsums[i >> 8];
    rowptr[i] = v;
    cursor[i] = v;
  }
  if (i == N) rowptr[N] = etot;
}

__global__ void scatter_kernel(const int* __restrict__ ei, int E, int N,
                               int* __restrict__ cursor, int* __restrict__ csr_src) {
  int e = blockIdx.x * blockDim.x + threadIdx.x;
  int etot = E + N;
  if (e >= etot) return;
  int s, d;
  if (e < E) { s = ei[e]; d = ei[E + e]; } else { s = e - E; d = e - E; }
  int pos = atomicAdd(&cursor[d], 1);
  csr_src[pos] = s;
}

// ---------------- degree counting-sort, LDS-aggregated ----------------
__global__ void deghist_kernel(const int* __restrict__ rowptr, int N,
                               int* __restrict__ dhist) {
  __shared__ int lh[1024];
  int t = threadIdx.x;
  for (int i = t; i < 1024; i += 256) lh[i] = 0;
  __syncthreads();
  int i = blockIdx.x * 256 + t;
  if (i < N) {
    int d = rowptr[i + 1] - rowptr[i];
    int key = d < 1023 ? d : 1023;
    atomicAdd(&lh[key], 1);
  }
  __syncthreads();
  for (int bin = t; bin < 1024; bin += 256) {
    int c = lh[bin];
    if (c) atomicAdd(&dhist[bin], c);
  }
}

__global__ void degscan_kernel(int* __restrict__ dhist) {  // 1 block x 1024
  __shared__ int sm[1024];
  int t = threadIdx.x;
  int v = dhist[t];
  sm[t] = v;
  __syncthreads();
#pragma unroll
  for (int off = 1; off < 1024; off <<= 1) {
    int add = (t >= off) ? sm[t - off] : 0;
    __syncthreads();
    sm[t] += add;
    __syncthreads();
  }
  dhist[t] = sm[t] - v;  // exclusive
}

__global__ void degscatter_kernel(const int* __restrict__ rowptr, int N,
                                  int* __restrict__ dhist, int* __restrict__ perm) {
  __shared__ int lc[1024];
  __shared__ int lb[1024];
  int t = threadIdx.x;
  for (int i = t; i < 1024; i += 256) lc[i] = 0;
  __syncthreads();
  int i = blockIdx.x * 256 + t;
  int key = 0, lr = 0;
  if (i < N) {
    int d = rowptr[i + 1] - rowptr[i];
    key = d < 1023 ? d : 1023;
    lr = atomicAdd(&lc[key], 1);
  }
  __syncthreads();
  for (int bin = t; bin < 1024; bin += 256) {
    int c = lc[bin];
    if (c) lb[bin] = atomicAdd(&dhist[bin], c);
  }
  __syncthreads();
  if (i < N) perm[lb[key] + lr] = i;
}

// ------- GEMM: H(bf16) = X(N x 128, f32) @ W(128 x COLS) + hl/hr epilogue ----
template <int COLS>
__global__ __launch_bounds__(256) void gemm_kernel(
    const float* __restrict__ X, const float* __restrict__ W,
    const float* __restrict__ al, const float* __restrict__ ar,
    unsigned short* __restrict__ H, float* __restrict__ hl,
    float* __restrict__ hr, int N) {
  constexpr int KC = 64;
  constexpr int XS = KC + 4;  // 2-way bank alias (free)
  __shared__ float Ws[KC * COLS];
  __shared__ float Xs[64 * XS];
  const int tid = threadIdx.x;
  const int tx = tid & 15, ty = tid >> 4;
  const int r0 = blockIdx.x * 64;

  float acc[4][2][4];
#pragma unroll
  for (int i = 0; i < 4; ++i)
#pragma unroll
    for (int h = 0; h < 2; ++h)
#pragma unroll
      for (int j = 0; j < 4; ++j) acc[i][h][j] = 0.f;

  for (int k0 = 0; k0 < 128; k0 += KC) {
    __syncthreads();
    constexpr int WQ = KC * COLS / 4;
    const float4* wg = (const float4*)(W + k0 * COLS);
#pragma unroll
    for (int i = tid; i < WQ; i += 256) ((float4*)Ws)[i] = wg[i];
#pragma unroll
    for (int i = tid; i < 64 * KC / 4; i += 256) {
      int row = i >> 4;
      int kq = i & 15;
      int gr = r0 + row;
      if (gr > N - 1) gr = N - 1;
      float4 v = *(const float4*)(X + (size_t)gr * 128 + k0 + kq * 4);
      *(float4*)(&Xs[row * XS + kq * 4]) = v;
    }
    __syncthreads();
#pragma unroll
    for (int kk0 = 0; kk0 < KC; kk0 += 4) {
      float4 xv[4];
#pragma unroll
      for (int i = 0; i < 4; ++i)
        xv[i] = *(const float4*)(&Xs[(ty * 4 + i) * XS + kk0]);
#pragma unroll
      for (int t = 0; t < 4; ++t) {
        float4 w0 = *(const float4*)(&Ws[(kk0 + t) * COLS + tx * 4]);
        float4 w1;
        if constexpr (COLS == 128) w1 = *(const float4*)(&Ws[(kk0 + t) * COLS + 64 + tx * 4]);
#pragma unroll
        for (int i = 0; i < 4; ++i) {
          float xk = f4c(xv[i], t);
          acc[i][0][0] = fmaf(xk, w0.x, acc[i][0][0]);
          acc[i][0][1] = fmaf(xk, w0.y, acc[i][0][1]);
          acc[i][0][2] = fmaf(xk, w0.z, acc[i][0][2]);
          acc[i][0][3] = fmaf(xk, w0.w, acc[i][0][3]);
          if constexpr (COLS == 128) {
            acc[i][1][0] = fmaf(xk, w1.x, acc[i][1][0]);
            acc[i][1][1] = fmaf(xk, w1.y, acc[i][1][1]);
            acc[i][1][2] = fmaf(xk, w1.z, acc[i][1][2]);
            acc[i][1][3] = fmaf(xk, w1.w, acc[i][1][3]);
          }
        }
      }
    }
  }

  float4 alv0 = *(const float4*)(al + tx * 4);
  float4 arv0 = *(const float4*)(ar + tx * 4);
  float4 alv1, arv1;
  if constexpr (COLS == 128) {
    alv1 = *(const float4*)(al + 64 + tx * 4);
    arv1 = *(const float4*)(ar + 64 + tx * 4);
  }
#pragma unroll
  for (int i = 0; i < 4; ++i) {
    int r = r0 + ty * 4 + i;
    bool ok = r < N;
    float4 o0 = make_float4(acc[i][0][0], acc[i][0][1], acc[i][0][2], acc[i][0][3]);
    float pl = o0.x * alv0.x + o0.y * alv0.y + o0.z * alv0.z + o0.w * alv0.w;
    float pr = o0.x * arv0.x + o0.y * arv0.y + o0.z * arv0.z + o0.w * arv0.w;
    if (ok) {
      uint2 pk = make_uint2(f2bf_pack(o0.x, o0.y), f2bf_pack(o0.z, o0.w));
      *(uint2*)(H + (size_t)r * COLS + tx * 4) = pk;
    }
    if constexpr (COLS == 128) {
      float4 o1 = make_float4(acc[i][1][0], acc[i][1][1], acc[i][1][2], acc[i][1][3]);
      pl += o1.x * alv1.x + o1.y * alv1.y + o1.z * alv1.z + o1.w * alv1.w;
      pr += o1.x * arv1.x + o1.y * arv1.y + o1.z * arv1.z + o1.w * arv1.w;
      if (ok) {
        uint2 pk = make_uint2(f2bf_pack(o1.x, o1.y), f2bf_pack(o1.z, o1.w));
        *(uint2*)(H + (size_t)r * COLS + 64 + tx * 4) = pk;
      }
    }
#pragma unroll
    for (int off = 1; off < 16; off <<= 1) {
      pl += __shfl_xor(pl, off);
      pr += __shfl_xor(pr, off);
    }
    if (ok && tx == 0) {
      hl[r] = pl;
      hr[r] = pr;
    }
  }
}

// ---------------- per-node attention + aggregation ----------------
// Wave = 8 groups x 8 lanes; each GROUP owns one node; octile-strided schedule
// (group g of chunk c -> sorted node g*C + c) for flat occupancy.
// H is bf16: lane l gathers EPL elements = EPL/2 uints (2 bf16 each).
// csr_src prefetched 2 ahead; H row + hl prefetched 1 ahead. Defer-max softmax.
template <int COLS, bool LAST>
__global__ __launch_bounds__(256) void node_kernel(
    const unsigned short* __restrict__ H, const float* __restrict__ hl,
    const float* __restrict__ hr, const int* __restrict__ rowptr,
    const int* __restrict__ csr_src, const int* __restrict__ perm,
    const float* __restrict__ b, float* __restrict__ OUT, int N) {
  constexpr int GS = 8;
  constexpr int EPL = COLS / GS;   // 16 (COLS=128) or 8 (COLS=64)
  constexpr int NU = EPL / 2;      // uints per lane (2 bf16 each)
  constexpr int NUQ = NU / 4;      // uint4 loads per lane: 2 or 1
  constexpr int NF4 = EPL / 4;
  const int lane = threadIdx.x & 63;
  const int g = lane >> 3, l = lane & 7;
  const int C = (N + GS - 1) / GS;
  const int c = blockIdx.x * 4 + (threadIdx.x >> 6);
  const int idx = g * C + c;
  const bool active = (c < C) && (idx < N);
  const int node = active ? perm[idx] : 0;

  float hi[EPL];
  {
    const uint4* hp = (const uint4*)(H + (size_t)node * COLS + l * EPL);
#pragma unroll
    for (int q = 0; q < NUQ; ++q) {
      uint4 u = hp[q];
      hi[q * 8 + 0] = bflo(u.x); hi[q * 8 + 1] = bfhi(u.x);
      hi[q * 8 + 2] = bflo(u.y); hi[q * 8 + 3] = bfhi(u.y);
      hi[q * 8 + 4] = bflo(u.z); hi[q * 8 + 5] = bfhi(u.z);
      hi[q * 8 + 6] = bflo(u.w); hi[q * 8 + 7] = bfhi(u.w);
    }
  }
  const float hri = hr[node];
  int e = active ? rowptr[node] : 0;
  const int end = active ? rowptr[node + 1] : 0;

  float m = -INFINITY, sumw = 0.f;
  float acc[EPL];
#pragma unroll
  for (int j = 0; j < EPL; ++j) acc[j] = 0.f;

  float hls;
  uint4 hv[NUQ];
  int sB = 0;
  if (e < end) {
    int s0 = csr_src[e];
    hls = hl[s0];
    const uint4* hp = (const uint4*)(H + (size_t)s0 * COLS + l * EPL);
#pragma unroll
    for (int q = 0; q < NUQ; ++q) hv[q] = hp[q];
    if (e + 1 < end) sB = csr_src[e + 1];
  }

  for (; e < end; ++e) {
    float ch[EPL];
#pragma unroll
    for (int q = 0; q < NUQ; ++q) {
      uint4 u = hv[q];
      ch[q * 8 + 0] = bflo(u.x); ch[q * 8 + 1] = bfhi(u.x);
      ch[q * 8 + 2] = bflo(u.y); ch[q * 8 + 3] = bfhi(u.y);
      ch[q * 8 + 4] = bflo(u.z); ch[q * 8 + 5] = bfhi(u.z);
      ch[q * 8 + 6] = bflo(u.w); ch[q * 8 + 7] = bfhi(u.w);
    }
    const float chl = hls;
    if (e + 1 < end) {  // issue next-edge gather (index already resident)
      hls = hl[sB];
      const uint4* hp = (const uint4*)(H + (size_t)sB * COLS + l * EPL);
#pragma unroll
      for (int q = 0; q < NUQ; ++q) hv[q] = hp[q];
    }
    int sC = (e + 2 < end) ? csr_src[e + 2] : 0;
    float d = 0.f;
#pragma unroll
    for (int j = 0; j < EPL; ++j) d = fmaf(hi[j], ch[j], d);
    d += __shfl_xor(d, 1);
    d += __shfl_xor(d, 2);
    d += __shfl_xor(d, 4);
    float gate = 1.f / (1.f + __expf(-d));
    float a = (chl + hri) * gate;
    a = (a >= 0.f) ? a : 0.2f * a;
    float dm = a - m;
    if (dm > 30.f) {             // first edge (m=-inf) or rare big jump
      float sc = __expf(-dm);
      sumw *= sc;
#pragma unroll
      for (int j = 0; j < EPL; ++j) acc[j] *= sc;
      m = a;
      dm = 0.f;
    }
    float w = __expf(dm);        // bounded by e^30 - f32 safe
    sumw += w;
#pragma unroll
    for (int j = 0; j < EPL; ++j) acc[j] = fmaf(w, ch[j], acc[j]);
    sB = sC;
  }

  if (!active) return;
  const float inv = 1.f / (sumw + 1e-16f);
  float o[EPL];
  const float* bp = b + l * EPL;
#pragma unroll
  for (int j = 0; j < EPL; ++j) o[j] = fmaxf(acc[j] * inv + bp[j], 0.f);

  if constexpr (LAST) {
    // COLS == 64, EPL == 8: log_softmax over the group's 64 values
    float mx = o[0];
#pragma unroll
    for (int j = 1; j < EPL; ++j) mx = fmaxf(mx, o[j]);
    mx = fmaxf(mx, __shfl_xor(mx, 1));
    mx = fmaxf(mx, __shfl_xor(mx, 2));
    mx = fmaxf(mx, __shfl_xor(mx, 4));
    float es = 0.f;
#pragma unroll
    for (int j = 0; j < EPL; ++j) es += __expf(o[j] - mx);
    es += __shfl_xor(es, 1);
    es += __shfl_xor(es, 2);
    es += __shfl_xor(es, 4);
    float ls = logf(es);
#pragma unroll
    for (int q = 0; q < NF4; ++q) {
      float4 ov = make_float4(o[q * 4 + 0] - mx - ls, o[q * 4 + 1] - mx - ls,
                              o[q * 4 + 2] - mx - ls, o[q * 4 + 3] - mx - ls);
      *(float4*)(&OUT[(size_t)node * COLS + l * EPL + q * 4]) = ov;
    }
  } else {
#pragma unroll
    for (int q = 0; q < NF4; ++q) {
      float4 ov = make_float4(o[q * 4 + 0], o[q * 4 + 1], o[q * 4 + 2], o[q * 4 + 3]);
      *(float4*)(&OUT[(size_t)node * COLS + l * EPL + q * 4]) = ov;
    }
  }
}

// ---------------- launch ----------------
extern "C" void kernel_launch(void* const* d_in, const int* in_sizes, int n_in,
                              void* d_out, int out_size, void* d_ws, size_t ws_size,
                              hipStream_t stream) {
  const float* x = (const float*)d_in[0];
  const int* ei = (const int*)d_in[1];
  const float* W0 = (const float*)d_in[2];
  const float* al0 = (const float*)d_in[3];
  const float* ar0 = (const float*)d_in[4];
  const float* b0 = (const float*)d_in[5];
  const float* W1 = (const float*)d_in[6];
  const float* al1 = (const float*)d_in[7];
  const float* ar1 = (const float*)d_in[8];
  const float* b1 = (const float*)d_in[9];
  const float* W2 = (const float*)d_in[10];
  const float* al2 = (const float*)d_in[11];
  const float* ar2 = (const float*)d_in[12];
  const float* b2 = (const float*)d_in[13];

  const int N = in_sizes[0] / 128;  // 50000
  const int E = in_sizes[1] / 2;    // 640000
  const int ETOT = E + N;

  char* p = (char*)d_ws;
  auto carve = [&](size_t bytes) {
    void* r = (void*)p;
    p += (bytes + 255) & ~(size_t)255;
    return r;
  };
  unsigned short* hA = (unsigned short*)carve((size_t)N * 128 * 2);  // bf16 H
  float* hB = (float*)carve((size_t)N * 128 * sizeof(float));        // f32 layer out
  float* hl = (float*)carve((size_t)N * sizeof(float));
  float* hr = (float*)carve((size_t)N * sizeof(float));
  int* counts = (int*)carve((size_t)N * sizeof(int));
  int* excl = (int*)carve((size_t)N * sizeof(int));
  int* bsums = (int*)carve(1024 * sizeof(int));
  int* rowptr = (int*)carve((size_t)(N + 1) * sizeof(int));
  int* cursor = (int*)carve((size_t)(N + 1) * sizeof(int));
  int* csr_src = (int*)carve((size_t)ETOT * sizeof(int));
  int* dhist = (int*)carve(1024 * sizeof(int));
  int* perm = (int*)carve((size_t)N * sizeof(int));

  // ---- CSR build ----
  hipMemsetAsync(counts, 0, (size_t)N * sizeof(int), stream);
  hipMemsetAsync(dhist, 0, 1024 * sizeof(int), stream);
  {
    int nb = (ETOT + 255) / 256;
    histo_kernel<<<nb, 256, 0, stream>>>(ei, E, N, counts);
  }
  int nbs = (N + 255) / 256;
  scan1_kernel<<<nbs, 256, 0, stream>>>(counts, excl, bsums, N);
  scan2_kernel<<<1, 256, 0, stream>>>(bsums, nbs);
  scan3_kernel<<<(N + 256) / 256 + 1, 256, 0, stream>>>(excl, bsums, rowptr, cursor, N, ETOT);
  {
    int nb = (ETOT + 255) / 256;
    scatter_kernel<<<nb, 256, 0, stream>>>(ei, E, N, cursor, csr_src);
  }
  // ---- degree sort (LDS-aggregated counting sort) ----
  deghist_kernel<<<nbs, 256, 0, stream>>>(rowptr, N, dhist);
  degscan_kernel<<<1, 1024, 0, stream>>>(dhist);
  degscatter_kernel<<<nbs, 256, 0, stream>>>(rowptr, N, dhist, perm);

  const int gemm_grid = (N + 63) / 64;
  const int C = (N + 7) / 8;
  const int node_grid = (C + 3) / 4;

  gemm_kernel<128><<<gemm_grid, 256, 0, stream>>>(x, W0, al0, ar0, hA, hl, hr, N);
  node_kernel<128, false><<<node_grid, 256, 0, stream>>>(hA, hl, hr, rowptr, csr_src, perm, b0, hB, N);

  gemm_kernel<128><<<gemm_grid, 256, 0, stream>>>(hB, W1, al1, ar1, hA, hl, hr, N);
  node_kernel<128, false><<<node_grid, 256, 0, stream>>>(hA, hl, hr, rowptr, csr_src, perm, b1, hB, N);

  gemm_kernel<64><<<gemm_grid, 256, 0, stream>>>(hB, W2, al2, ar2, hA, hl, hr, N);
  node_kernel<64, true><<<node_grid, 256, 0, stream>>>(hA, hl, hr, rowptr, csr_src, perm, b2,
                                                       (float*)d_out, N);
}

// Round 9
// 234.912 us; speedup vs baseline: 1.4696x; 1.2883x over previous
//
#include <hip/hip_runtime.h>
#include <math.h>

using short8 = __attribute__((ext_vector_type(8))) short;
using f32x4 = __attribute__((ext_vector_type(4))) float;

// bf16 helpers
__device__ __forceinline__ float bflo(unsigned int u) {
  union { unsigned int i; float f; } v; v.i = u << 16; return v.f;
}
__device__ __forceinline__ float bfhi(unsigned int u) {
  union { unsigned int i; float f; } v; v.i = u & 0xFFFF0000u; return v.f;
}
__device__ __forceinline__ unsigned short f2bf1(float f) {  // RNE
  union { float f; unsigned int i; } v; v.f = f;
  return (unsigned short)((v.i + 0x7FFFu + ((v.i >> 16) & 1u)) >> 16);
}
__device__ __forceinline__ unsigned int f2bf_pack(float a, float b) {  // RNE
  union { float f; unsigned int i; } x, y; x.f = a; y.f = b;
  unsigned int xa = x.i + 0x7FFFu + ((x.i >> 16) & 1u);
  unsigned int yb = y.i + 0x7FFFu + ((y.i >> 16) & 1u);
  return (xa >> 16) | (yb & 0xFFFF0000u);
}

// ---------------- CSR build ----------------
__global__ void histo_kernel(const int* __restrict__ ei, int E, int N,
                             int* __restrict__ counts) {
  int e = blockIdx.x * blockDim.x + threadIdx.x;
  int etot = E + N;
  if (e >= etot) return;
  int d = (e < E) ? ei[E + e] : (e - E);
  atomicAdd(&counts[d], 1);
}

__global__ void scan1_kernel(const int* __restrict__ counts, int* __restrict__ excl,
                             int* __restrict__ bsums, int N) {
  __shared__ int sm[256];
  int t = threadIdx.x;
  int i = blockIdx.x * 256 + t;
  int v = (i < N) ? counts[i] : 0;
  sm[t] = v;
  __syncthreads();
#pragma unroll
  for (int off = 1; off < 256; off <<= 1) {
    int add = (t >= off) ? sm[t - off] : 0;
    __syncthreads();
    sm[t] += add;
    __syncthreads();
  }
  if (i < N) excl[i] = sm[t] - v;
  if (t == 255) bsums[blockIdx.x] = sm[255];
}

__global__ void scan2_kernel(int* __restrict__ bsums, int nb) {
  __shared__ int sm[256];
  int t = threadIdx.x;
  int v = (t < nb) ? bsums[t] : 0;
  sm[t] = v;
  __syncthreads();
#pragma unroll
  for (int off = 1; off < 256; off <<= 1) {
    int add = (t >= off) ? sm[t - off] : 0;
    __syncthreads();
    sm[t] += add;
    __syncthreads();
  }
  if (t < nb) bsums[t] = sm[t] - v;  // exclusive
}

__global__ void scan3_kernel(const int* __restrict__ excl, const int* __restrict__ bsums,
                             int* __restrict__ rowptr, int* __restrict__ cursor,
                             int N, int etot) {
  int i = blockIdx.x * 256 + threadIdx.x;
  if (i < N) {
    int v = excl[i] + bsums[i >> 8];
    rowptr[i] = v;
    cursor[i] = v;
  }
  if (i == N) rowptr[N] = etot;
}

__global__ void scatter_kernel(const int* __restrict__ ei, int E, int N,
                               int* __restrict__ cursor, int* __restrict__ csr_src) {
  int e = blockIdx.x * blockDim.x + threadIdx.x;
  int etot = E + N;
  if (e >= etot) return;
  int s, d;
  if (e < E) { s = ei[e]; d = ei[E + e]; } else { s = e - E; d = e - E; }
  int pos = atomicAdd(&cursor[d], 1);
  csr_src[pos] = s;
}

// ---------------- degree counting-sort, LDS-aggregated ----------------
__global__ void deghist_kernel(const int* __restrict__ rowptr, int N,
                               int* __restrict__ dhist) {
  __shared__ int lh[1024];
  int t = threadIdx.x;
  for (int i = t; i < 1024; i += 256) lh[i] = 0;
  __syncthreads();
  int i = blockIdx.x * 256 + t;
  if (i < N) {
    int d = rowptr[i + 1] - rowptr[i];
    int key = d < 1023 ? d : 1023;
    atomicAdd(&lh[key], 1);
  }
  __syncthreads();
  for (int bin = t; bin < 1024; bin += 256) {
    int c = lh[bin];
    if (c) atomicAdd(&dhist[bin], c);
  }
}

__global__ void degscan_kernel(int* __restrict__ dhist) {  // 1 block x 1024
  __shared__ int sm[1024];
  int t = threadIdx.x;
  int v = dhist[t];
  sm[t] = v;
  __syncthreads();
#pragma unroll
  for (int off = 1; off < 1024; off <<= 1) {
    int add = (t >= off) ? sm[t - off] : 0;
    __syncthreads();
    sm[t] += add;
    __syncthreads();
  }
  dhist[t] = sm[t] - v;  // exclusive
}

__global__ void degscatter_kernel(const int* __restrict__ rowptr, int N,
                                  int* __restrict__ dhist, int* __restrict__ perm) {
  __shared__ int lc[1024];
  __shared__ int lb[1024];
  int t = threadIdx.x;
  for (int i = t; i < 1024; i += 256) lc[i] = 0;
  __syncthreads();
  int i = blockIdx.x * 256 + t;
  int key = 0, lr = 0;
  if (i < N) {
    int d = rowptr[i + 1] - rowptr[i];
    key = d < 1023 ? d : 1023;
    lr = atomicAdd(&lc[key], 1);
  }
  __syncthreads();
  for (int bin = t; bin < 1024; bin += 256) {
    int c = lc[bin];
    if (c) lb[bin] = atomicAdd(&dhist[bin], c);
  }
  __syncthreads();
  if (i < N) perm[lb[key] + lr] = i;
}

// -------- W transpose + bf16 cast: Wt[c][k] (row stride 136) = W[k][c] -------
__global__ void wcast_kernel(const float* __restrict__ W,
                             unsigned short* __restrict__ Wt, int COLS) {
  int o = blockIdx.x * 256 + threadIdx.x;
  if (o >= 128 * COLS) return;
  int c = o >> 7;        // output row (column of W)
  int k = o & 127;
  Wt[c * 136 + k] = f2bf1(W[(size_t)k * COLS + c]);
}

// ------------- MFMA GEMM: H(bf16) = X @ W, fused hl/hr epilogue --------------
// Block = 256 thr = 4 waves; tile 64 rows x COLS. Wave w: rows r0+w*16..+15,
// all COLS cols (NT tiles of 16), K=128 in 4 steps of 32.
// A-frag: lane holds row (l&15), k = (l>>4)*8 + j  (from global, bf16 or f32)
// B-frag: lane holds col (l&15), k = (l>>4)*8 + j  (from LDS Wt, pad-136)
// C/D: col = l&15, row = (l>>4)*4 + reg   [verified gfx950 mapping]
template <int COLS, bool AF32>
__global__ __launch_bounds__(256) void gemm_mfma(
    const void* __restrict__ Xv, const unsigned short* __restrict__ Wt,
    const float* __restrict__ al, const float* __restrict__ ar,
    unsigned short* __restrict__ H, float* __restrict__ hl,
    float* __restrict__ hr, int N) {
  constexpr int NT = COLS / 16;  // n-tiles per wave
  __shared__ unsigned short Ws[COLS * 136];
  const int tid = threadIdx.x;
  {  // stage Wt (COLS*136 ushorts = COLS*68 uints)
    const unsigned int* wg = (const unsigned int*)Wt;
    unsigned int* ws = (unsigned int*)Ws;
    for (int i = tid; i < COLS * 68; i += 256) ws[i] = wg[i];
  }
  __syncthreads();

  const int w = tid >> 6, l = tid & 63;
  const int l15 = l & 15, lg = l >> 4;
  const int r0 = blockIdx.x * 64 + w * 16;

  f32x4 acc[NT];
#pragma unroll
  for (int t = 0; t < NT; ++t)
#pragma unroll
    for (int j = 0; j < 4; ++j) acc[t][j] = 0.f;

  int arow = r0 + l15;
  if (arow > N - 1) arow = N - 1;

#pragma unroll
  for (int ks = 0; ks < 4; ++ks) {
    short8 af;
    if constexpr (AF32) {
      const float* xp = (const float*)Xv + (size_t)arow * 128 + ks * 32 + lg * 8;
      float4 x0 = *(const float4*)xp;
      float4 x1 = *(const float4*)(xp + 4);
      af[0] = (short)f2bf1(x0.x); af[1] = (short)f2bf1(x0.y);
      af[2] = (short)f2bf1(x0.z); af[3] = (short)f2bf1(x0.w);
      af[4] = (short)f2bf1(x1.x); af[5] = (short)f2bf1(x1.y);
      af[6] = (short)f2bf1(x1.z); af[7] = (short)f2bf1(x1.w);
    } else {
      af = *(const short8*)((const unsigned short*)Xv + (size_t)arow * 128 + ks * 32 + lg * 8);
    }
#pragma unroll
    for (int t = 0; t < NT; ++t) {
      short8 bf = *(const short8*)(&Ws[(t * 16 + l15) * 136 + ks * 32 + lg * 8]);
      acc[t] = __builtin_amdgcn_mfma_f32_16x16x32_bf16(af, bf, acc[t], 0, 0, 0);
    }
  }

  // epilogue: lane holds col (l15) of each tile, rows lg*4+reg
  const int orow = r0 + lg * 4;
  float pl4[4] = {0.f, 0.f, 0.f, 0.f}, pr4[4] = {0.f, 0.f, 0.f, 0.f};
#pragma unroll
  for (int t = 0; t < NT; ++t) {
    float av = al[t * 16 + l15], rv = ar[t * 16 + l15];
#pragma unroll
    for (int r = 0; r < 4; ++r) {
      pl4[r] = fmaf(acc[t][r], av, pl4[r]);
      pr4[r] = fmaf(acc[t][r], rv, pr4[r]);
    }
    // H store (bf16): 16 lanes -> 32B contiguous per (reg, group)
#pragma unroll
    for (int r = 0; r < 4; ++r) {
      int row = orow + r;
      if (row < N) H[(size_t)row * COLS + t * 16 + l15] = f2bf1(acc[t][r]);
    }
  }
  // reduce cols across the 16 lanes of this group
#pragma unroll
  for (int off = 1; off < 16; off <<= 1) {
#pragma unroll
    for (int r = 0; r < 4; ++r) {
      pl4[r] += __shfl_xor(pl4[r], off);
      pr4[r] += __shfl_xor(pr4[r], off);
    }
  }
  if (l15 == 0) {
#pragma unroll
    for (int r = 0; r < 4; ++r) {
      int row = orow + r;
      if (row < N) { hl[row] = pl4[r]; hr[row] = pr4[r]; }
    }
  }
}

// ---------------- per-node attention + aggregation ----------------
// Wave = 8 groups x 8 lanes; each GROUP owns one node; octile-strided schedule.
// H bf16; non-last layers write bf16 output (next GEMM's A), last writes f32.
template <int COLS, bool LAST>
__global__ __launch_bounds__(256) void node_kernel(
    const unsigned short* __restrict__ H, const float* __restrict__ hl,
    const float* __restrict__ hr, const int* __restrict__ rowptr,
    const int* __restrict__ csr_src, const int* __restrict__ perm,
    const float* __restrict__ b, void* __restrict__ OUTv, int N) {
  constexpr int GS = 8;
  constexpr int EPL = COLS / GS;   // 16 (COLS=128) or 8 (COLS=64)
  constexpr int NU = EPL / 2;      // uints per lane
  constexpr int NUQ = NU / 4;      // uint4 loads per lane
  constexpr int NF4 = EPL / 4;
  const int lane = threadIdx.x & 63;
  const int g = lane >> 3, l = lane & 7;
  const int C = (N + GS - 1) / GS;
  const int c = blockIdx.x * 4 + (threadIdx.x >> 6);
  const int idx = g * C + c;
  const bool active = (c < C) && (idx < N);
  const int node = active ? perm[idx] : 0;

  float hi[EPL];
  {
    const uint4* hp = (const uint4*)(H + (size_t)node * COLS + l * EPL);
#pragma unroll
    for (int q = 0; q < NUQ; ++q) {
      uint4 u = hp[q];
      hi[q * 8 + 0] = bflo(u.x); hi[q * 8 + 1] = bfhi(u.x);
      hi[q * 8 + 2] = bflo(u.y); hi[q * 8 + 3] = bfhi(u.y);
      hi[q * 8 + 4] = bflo(u.z); hi[q * 8 + 5] = bfhi(u.z);
      hi[q * 8 + 6] = bflo(u.w); hi[q * 8 + 7] = bfhi(u.w);
    }
  }
  const float hri = hr[node];
  int e = active ? rowptr[node] : 0;
  const int end = active ? rowptr[node + 1] : 0;

  float m = -INFINITY, sumw = 0.f;
  float acc[EPL];
#pragma unroll
  for (int j = 0; j < EPL; ++j) acc[j] = 0.f;

  float hls;
  uint4 hv[NUQ];
  int sB = 0;
  if (e < end) {
    int s0 = csr_src[e];
    hls = hl[s0];
    const uint4* hp = (const uint4*)(H + (size_t)s0 * COLS + l * EPL);
#pragma unroll
    for (int q = 0; q < NUQ; ++q) hv[q] = hp[q];
    if (e + 1 < end) sB = csr_src[e + 1];
  }

  for (; e < end; ++e) {
    float ch[EPL];
#pragma unroll
    for (int q = 0; q < NUQ; ++q) {
      uint4 u = hv[q];
      ch[q * 8 + 0] = bflo(u.x); ch[q * 8 + 1] = bfhi(u.x);
      ch[q * 8 + 2] = bflo(u.y); ch[q * 8 + 3] = bfhi(u.y);
      ch[q * 8 + 4] = bflo(u.z); ch[q * 8 + 5] = bfhi(u.z);
      ch[q * 8 + 6] = bflo(u.w); ch[q * 8 + 7] = bfhi(u.w);
    }
    const float chl = hls;
    if (e + 1 < end) {  // issue next-edge gather (index already resident)
      hls = hl[sB];
      const uint4* hp = (const uint4*)(H + (size_t)sB * COLS + l * EPL);
#pragma unroll
      for (int q = 0; q < NUQ; ++q) hv[q] = hp[q];
    }
    int sC = (e + 2 < end) ? csr_src[e + 2] : 0;
    float d = 0.f;
#pragma unroll
    for (int j = 0; j < EPL; ++j) d = fmaf(hi[j], ch[j], d);
    d += __shfl_xor(d, 1);
    d += __shfl_xor(d, 2);
    d += __shfl_xor(d, 4);
    float gate = 1.f / (1.f + __expf(-d));
    float a = (chl + hri) * gate;
    a = (a >= 0.f) ? a : 0.2f * a;
    float dm = a - m;
    if (dm > 30.f) {             // first edge (m=-inf) or rare big jump
      float sc = __expf(-dm);
      sumw *= sc;
#pragma unroll
      for (int j = 0; j < EPL; ++j) acc[j] *= sc;
      m = a;
      dm = 0.f;
    }
    float w = __expf(dm);        // bounded by e^30 - f32 safe
    sumw += w;
#pragma unroll
    for (int j = 0; j < EPL; ++j) acc[j] = fmaf(w, ch[j], acc[j]);
    sB = sC;
  }

  if (!active) return;
  const float inv = 1.f / (sumw + 1e-16f);
  float o[EPL];
  const float* bp = b + l * EPL;
#pragma unroll
  for (int j = 0; j < EPL; ++j) o[j] = fmaxf(acc[j] * inv + bp[j], 0.f);

  if constexpr (LAST) {
    // COLS == 64, EPL == 8: log_softmax over the group's 64 values -> f32 out
    float* OUT = (float*)OUTv;
    float mx = o[0];
#pragma unroll
    for (int j = 1; j < EPL; ++j) mx = fmaxf(mx, o[j]);
    mx = fmaxf(mx, __shfl_xor(mx, 1));
    mx = fmaxf(mx, __shfl_xor(mx, 2));
    mx = fmaxf(mx, __shfl_xor(mx, 4));
    float es = 0.f;
#pragma unroll
    for (int j = 0; j < EPL; ++j) es += __expf(o[j] - mx);
    es += __shfl_xor(es, 1);
    es += __shfl_xor(es, 2);
    es += __shfl_xor(es, 4);
    float ls = logf(es);
#pragma unroll
    for (int q = 0; q < NF4; ++q) {
      float4 ov = make_float4(o[q * 4 + 0] - mx - ls, o[q * 4 + 1] - mx - ls,
                              o[q * 4 + 2] - mx - ls, o[q * 4 + 3] - mx - ls);
      *(float4*)(&OUT[(size_t)node * COLS + l * EPL + q * 4]) = ov;
    }
  } else {
    // bf16 output (next layer's GEMM A operand)
    unsigned short* OUT = (unsigned short*)OUTv;
    unsigned int pk[NU];
#pragma unroll
    for (int u = 0; u < NU; ++u) pk[u] = f2bf_pack(o[2 * u], o[2 * u + 1]);
    unsigned int* op = (unsigned int*)(OUT + (size_t)node * COLS + l * EPL);
#pragma unroll
    for (int q = 0; q < NUQ; ++q)
      *(uint4*)(op + q * 4) = make_uint4(pk[q * 4 + 0], pk[q * 4 + 1],
                                         pk[q * 4 + 2], pk[q * 4 + 3]);
  }
}

// ---------------- launch ----------------
extern "C" void kernel_launch(void* const* d_in, const int* in_sizes, int n_in,
                              void* d_out, int out_size, void* d_ws, size_t ws_size,
                              hipStream_t stream) {
  const float* x = (const float*)d_in[0];
  const int* ei = (const int*)d_in[1];
  const float* W0 = (const float*)d_in[2];
  const float* al0 = (const float*)d_in[3];
  const float* ar0 = (const float*)d_in[4];
  const float* b0 = (const float*)d_in[5];
  const float* W1 = (const float*)d_in[6];
  const float* al1 = (const float*)d_in[7];
  const float* ar1 = (const float*)d_in[8];
  const float* b1 = (const float*)d_in[9];
  const float* W2 = (const float*)d_in[10];
  const float* al2 = (const float*)d_in[11];
  const float* ar2 = (const float*)d_in[12];
  const float* b2 = (const float*)d_in[13];

  const int N = in_sizes[0] / 128;  // 50000
  const int E = in_sizes[1] / 2;    // 640000
  const int ETOT = E + N;

  char* p = (char*)d_ws;
  auto carve = [&](size_t bytes) {
    void* r = (void*)p;
    p += (bytes + 255) & ~(size_t)255;
    return r;
  };
  unsigned short* Hb = (unsigned short*)carve((size_t)N * 128 * 2);  // bf16 GEMM out
  unsigned short* Ob = (unsigned short*)carve((size_t)N * 128 * 2);  // bf16 node out
  float* hl = (float*)carve((size_t)N * sizeof(float));
  float* hr = (float*)carve((size_t)N * sizeof(float));
  int* counts = (int*)carve((size_t)N * sizeof(int));
  int* excl = (int*)carve((size_t)N * sizeof(int));
  int* bsums = (int*)carve(1024 * sizeof(int));
  int* rowptr = (int*)carve((size_t)(N + 1) * sizeof(int));
  int* cursor = (int*)carve((size_t)(N + 1) * sizeof(int));
  int* csr_src = (int*)carve((size_t)ETOT * sizeof(int));
  int* dhist = (int*)carve(1024 * sizeof(int));
  int* perm = (int*)carve((size_t)N * sizeof(int));
  unsigned short* Wt0 = (unsigned short*)carve(128 * 136 * 2);
  unsigned short* Wt1 = (unsigned short*)carve(128 * 136 * 2);
  unsigned short* Wt2 = (unsigned short*)carve(64 * 136 * 2);

  // ---- W transpose+cast (tiny, independent) ----
  wcast_kernel<<<(128 * 128 + 255) / 256, 256, 0, stream>>>(W0, Wt0, 128);
  wcast_kernel<<<(128 * 128 + 255) / 256, 256, 0, stream>>>(W1, Wt1, 128);
  wcast_kernel<<<(128 * 64 + 255) / 256, 256, 0, stream>>>(W2, Wt2, 64);

  // ---- CSR build ----
  hipMemsetAsync(counts, 0, (size_t)N * sizeof(int), stream);
  hipMemsetAsync(dhist, 0, 1024 * sizeof(int), stream);
  {
    int nb = (ETOT + 255) / 256;
    histo_kernel<<<nb, 256, 0, stream>>>(ei, E, N, counts);
  }
  int nbs = (N + 255) / 256;
  scan1_kernel<<<nbs, 256, 0, stream>>>(counts, excl, bsums, N);
  scan2_kernel<<<1, 256, 0, stream>>>(bsums, nbs);
  scan3_kernel<<<(N + 256) / 256 + 1, 256, 0, stream>>>(excl, bsums, rowptr, cursor, N, ETOT);
  {
    int nb = (ETOT + 255) / 256;
    scatter_kernel<<<nb, 256, 0, stream>>>(ei, E, N, cursor, csr_src);
  }
  // ---- degree sort ----
  deghist_kernel<<<nbs, 256, 0, stream>>>(rowptr, N, dhist);
  degscan_kernel<<<1, 1024, 0, stream>>>(dhist);
  degscatter_kernel<<<nbs, 256, 0, stream>>>(rowptr, N, dhist, perm);

  const int gemm_grid = (N + 63) / 64;
  const int C = (N + 7) / 8;
  const int node_grid = (C + 3) / 4;

  // layer 0: A = x (f32, cast in-flight)
  gemm_mfma<128, true><<<gemm_grid, 256, 0, stream>>>(x, Wt0, al0, ar0, Hb, hl, hr, N);
  node_kernel<128, false><<<node_grid, 256, 0, stream>>>(Hb, hl, hr, rowptr, csr_src, perm, b0, Ob, N);

  // layer 1: A = Ob (bf16)
  gemm_mfma<128, false><<<gemm_grid, 256, 0, stream>>>(Ob, Wt1, al1, ar1, Hb, hl, hr, N);
  node_kernel<128, false><<<node_grid, 256, 0, stream>>>(Hb, hl, hr, rowptr, csr_src, perm, b1, Ob, N);

  // layer 2: A = Ob (bf16), COLS = 64
  gemm_mfma<64, false><<<gemm_grid, 256, 0, stream>>>(Ob, Wt2, al2, ar2, Hb, hl, hr, N);
  node_kernel<64, true><<<node_grid, 256, 0, stream>>>(Hb, hl, hr, rowptr, csr_src, perm, b2,
                                                       d_out, N);
}

// Round 10
// 227.084 us; speedup vs baseline: 1.5203x; 1.0345x over previous
//
#include <hip/hip_runtime.h>
#include <math.h>

using short8 = __attribute__((ext_vector_type(8))) short;
using f32x4 = __attribute__((ext_vector_type(4))) float;

// bf16 helpers
__device__ __forceinline__ float bflo(unsigned int u) {
  union { unsigned int i; float f; } v; v.i = u << 16; return v.f;
}
__device__ __forceinline__ float bfhi(unsigned int u) {
  union { unsigned int i; float f; } v; v.i = u & 0xFFFF0000u; return v.f;
}
__device__ __forceinline__ unsigned short f2bf1(float f) {  // RNE
  union { float f; unsigned int i; } v; v.f = f;
  return (unsigned short)((v.i + 0x7FFFu + ((v.i >> 16) & 1u)) >> 16);
}
__device__ __forceinline__ unsigned int f2bf_pack(float a, float b) {  // RNE
  union { float f; unsigned int i; } x, y; x.f = a; y.f = b;
  unsigned int xa = x.i + 0x7FFFu + ((x.i >> 16) & 1u);
  unsigned int yb = y.i + 0x7FFFu + ((y.i >> 16) & 1u);
  return (xa >> 16) | (yb & 0xFFFF0000u);
}

// ---------- prep0: zero counts/dhist + transpose/cast all 3 weights ----------
__global__ void prep0_kernel(const float* __restrict__ W0, const float* __restrict__ W1,
                             const float* __restrict__ W2, unsigned short* __restrict__ Wt0,
                             unsigned short* __restrict__ Wt1, unsigned short* __restrict__ Wt2,
                             int* __restrict__ counts, int* __restrict__ dhist, int N) {
  int i = blockIdx.x * 256 + threadIdx.x;
  int gs = gridDim.x * 256;
  for (int j = i; j < N; j += gs) counts[j] = 0;
  if (i < 1024) dhist[i] = 0;
  for (int j = i; j < 128 * 128; j += gs) {
    int c = j >> 7, k = j & 127;
    Wt0[c * 136 + k] = f2bf1(W0[(size_t)k * 128 + c]);
  }
  for (int j = i; j < 128 * 128; j += gs) {
    int c = j >> 7, k = j & 127;
    Wt1[c * 136 + k] = f2bf1(W1[(size_t)k * 128 + c]);
  }
  for (int j = i; j < 64 * 128; j += gs) {
    int c = j >> 7, k = j & 127;
    Wt2[c * 136 + k] = f2bf1(W2[(size_t)k * 64 + c]);
  }
}

// ---------------- histo ----------------
__global__ void histo_kernel(const int* __restrict__ ei, int E, int N,
                             int* __restrict__ counts) {
  int e = blockIdx.x * blockDim.x + threadIdx.x;
  int etot = E + N;
  if (e >= etot) return;
  int d = (e < E) ? ei[E + e] : (e - E);
  atomicAdd(&counts[d], 1);
}

// ---------------- scan1 (per-256-chunk) + deghist fused ----------------
__global__ void scan1_deghist_kernel(const int* __restrict__ counts, int* __restrict__ excl,
                                     int* __restrict__ bsums, int* __restrict__ dhist, int N) {
  __shared__ int sm[256];
  __shared__ int lh[1024];
  int t = threadIdx.x;
  int i = blockIdx.x * 256 + t;
  int v = (i < N) ? counts[i] : 0;
  sm[t] = v;
  __syncthreads();
#pragma unroll
  for (int off = 1; off < 256; off <<= 1) {
    int add = (t >= off) ? sm[t - off] : 0;
    __syncthreads();
    sm[t] += add;
    __syncthreads();
  }
  if (i < N) excl[i] = sm[t] - v;
  if (t == 255) bsums[blockIdx.x] = sm[255];
  // deghist: degree of node i is v (counts before scan)
  for (int q = t; q < 1024; q += 256) lh[q] = 0;
  __syncthreads();
  if (i < N) {
    int key = v < 1023 ? v : 1023;
    atomicAdd(&lh[key], 1);
  }
  __syncthreads();
  for (int q = t; q < 1024; q += 256) {
    int c = lh[q];
    if (c) atomicAdd(&dhist[q], c);
  }
}

// ---------------- scan2 (block 0) + degscan-1024 (block 1) fused -------------
__global__ void scan2_degscan_kernel(int* __restrict__ bsums, int nb,
                                     int* __restrict__ dhist) {
  int t = threadIdx.x;
  if (blockIdx.x == 0) {
    __shared__ int sm[256];
    int v = (t < nb) ? bsums[t] : 0;
    sm[t] = v;
    __syncthreads();
#pragma unroll
    for (int off = 1; off < 256; off <<= 1) {
      int add = (t >= off) ? sm[t - off] : 0;
      __syncthreads();
      sm[t] += add;
      __syncthreads();
    }
    if (t < nb) bsums[t] = sm[t] - v;  // exclusive
  } else {
    __shared__ int arr[256];
    int v0 = dhist[t * 4 + 0], v1 = dhist[t * 4 + 1];
    int v2 = dhist[t * 4 + 2], v3 = dhist[t * 4 + 3];
    int s0 = v0, s1 = s0 + v1, s2 = s1 + v2, s3 = s2 + v3;  // thread-local incl
    arr[t] = s3;
    __syncthreads();
#pragma unroll
    for (int off = 1; off < 256; off <<= 1) {
      int add = (t >= off) ? arr[t - off] : 0;
      __syncthreads();
      arr[t] += add;
      __syncthreads();
    }
    int base = (t > 0) ? arr[t - 1] : 0;  // exclusive base for this thread's 4
    dhist[t * 4 + 0] = base;
    dhist[t * 4 + 1] = base + s0;
    dhist[t * 4 + 2] = base + s1;
    dhist[t * 4 + 3] = base + s2;
  }
}

// ---------------- scan3 ----------------
__global__ void scan3_kernel(const int* __restrict__ excl, const int* __restrict__ bsums,
                             int* __restrict__ rowptr, int* __restrict__ cursor,
                             int N, int etot) {
  int i = blockIdx.x * 256 + threadIdx.x;
  if (i < N) {
    int v = excl[i] + bsums[i >> 8];
    rowptr[i] = v;
    cursor[i] = v;
  }
  if (i == N) rowptr[N] = etot;
}

// ---------------- scatter + degscatter fused ----------------
__global__ void scatter_degscatter_kernel(const int* __restrict__ ei, int E, int N,
                                          int* __restrict__ cursor, int* __restrict__ csr_src,
                                          const int* __restrict__ rowptr,
                                          int* __restrict__ dhist, int* __restrict__ perm) {
  int t = threadIdx.x;
  int e = blockIdx.x * 256 + t;
  int etot = E + N;
  if (e < etot) {
    int s, d;
    if (e < E) { s = ei[e]; d = ei[E + e]; } else { s = e - E; d = e - E; }
    int pos = atomicAdd(&cursor[d], 1);
    csr_src[pos] = s;
  }
  if (blockIdx.x < (N + 255) / 256) {  // block-uniform branch
    __shared__ int lc[1024];
    __shared__ int lb[1024];
    for (int q = t; q < 1024; q += 256) lc[q] = 0;
    __syncthreads();
    int i = blockIdx.x * 256 + t;
    int key = 0, lr = 0;
    if (i < N) {
      int d = rowptr[i + 1] - rowptr[i];
      key = d < 1023 ? d : 1023;
      lr = atomicAdd(&lc[key], 1);
    }
    __syncthreads();
    for (int q = t; q < 1024; q += 256) {
      int c = lc[q];
      if (c) lb[q] = atomicAdd(&dhist[q], c);
    }
    __syncthreads();
    if (i < N) perm[lb[key] + lr] = i;
  }
}

// ------------- MFMA GEMM: H(bf16) = X @ W, fused hl/hr epilogue --------------
template <int COLS, bool AF32>
__global__ __launch_bounds__(256) void gemm_mfma(
    const void* __restrict__ Xv, const unsigned short* __restrict__ Wt,
    const float* __restrict__ al, const float* __restrict__ ar,
    unsigned short* __restrict__ H, float* __restrict__ hl,
    float* __restrict__ hr, int N) {
  constexpr int NT = COLS / 16;
  __shared__ unsigned short Ws[COLS * 136];
  const int tid = threadIdx.x;
  {
    const unsigned int* wg = (const unsigned int*)Wt;
    unsigned int* ws = (unsigned int*)Ws;
    for (int i = tid; i < COLS * 68; i += 256) ws[i] = wg[i];
  }
  __syncthreads();

  const int w = tid >> 6, l = tid & 63;
  const int l15 = l & 15, lg = l >> 4;
  const int r0 = blockIdx.x * 64 + w * 16;

  f32x4 acc[NT];
#pragma unroll
  for (int t = 0; t < NT; ++t)
#pragma unroll
    for (int j = 0; j < 4; ++j) acc[t][j] = 0.f;

  int arow = r0 + l15;
  if (arow > N - 1) arow = N - 1;

#pragma unroll
  for (int ks = 0; ks < 4; ++ks) {
    short8 af;
    if constexpr (AF32) {
      const float* xp = (const float*)Xv + (size_t)arow * 128 + ks * 32 + lg * 8;
      float4 x0 = *(const float4*)xp;
      float4 x1 = *(const float4*)(xp + 4);
      af[0] = (short)f2bf1(x0.x); af[1] = (short)f2bf1(x0.y);
      af[2] = (short)f2bf1(x0.z); af[3] = (short)f2bf1(x0.w);
      af[4] = (short)f2bf1(x1.x); af[5] = (short)f2bf1(x1.y);
      af[6] = (short)f2bf1(x1.z); af[7] = (short)f2bf1(x1.w);
    } else {
      af = *(const short8*)((const unsigned short*)Xv + (size_t)arow * 128 + ks * 32 + lg * 8);
    }
#pragma unroll
    for (int t = 0; t < NT; ++t) {
      short8 bf = *(const short8*)(&Ws[(t * 16 + l15) * 136 + ks * 32 + lg * 8]);
      acc[t] = __builtin_amdgcn_mfma_f32_16x16x32_bf16(af, bf, acc[t], 0, 0, 0);
    }
  }

  const int orow = r0 + lg * 4;
  float pl4[4] = {0.f, 0.f, 0.f, 0.f}, pr4[4] = {0.f, 0.f, 0.f, 0.f};
#pragma unroll
  for (int t = 0; t < NT; ++t) {
    float av = al[t * 16 + l15], rv = ar[t * 16 + l15];
#pragma unroll
    for (int r = 0; r < 4; ++r) {
      pl4[r] = fmaf(acc[t][r], av, pl4[r]);
      pr4[r] = fmaf(acc[t][r], rv, pr4[r]);
    }
#pragma unroll
    for (int r = 0; r < 4; ++r) {
      int row = orow + r;
      if (row < N) H[(size_t)row * COLS + t * 16 + l15] = f2bf1(acc[t][r]);
    }
  }
#pragma unroll
  for (int off = 1; off < 16; off <<= 1) {
#pragma unroll
    for (int r = 0; r < 4; ++r) {
      pl4[r] += __shfl_xor(pl4[r], off);
      pr4[r] += __shfl_xor(pr4[r], off);
    }
  }
  if (l15 == 0) {
#pragma unroll
    for (int r = 0; r < 4; ++r) {
      int row = orow + r;
      if (row < N) { hl[row] = pl4[r]; hr[row] = pr4[r]; }
    }
  }
}

// ---------------- per-node attention + aggregation ----------------
// Wave = 4 groups x 16 lanes; each GROUP owns one node (quartile-strided:
// group g of chunk c -> sorted node g*C + c, C = ceil(N/4) -> per-wave work
// uniform). 2-edge-deep H pipeline (hvA/hvB, statically indexed) + 4-deep
// csr_src index prefetch. Defer-max online softmax (THR=30).
template <int COLS, bool LAST>
__global__ __launch_bounds__(256, 6) void node_kernel(
    const unsigned short* __restrict__ H, const float* __restrict__ hl,
    const float* __restrict__ hr, const int* __restrict__ rowptr,
    const int* __restrict__ csr_src, const int* __restrict__ perm,
    const float* __restrict__ b, void* __restrict__ OUTv, int N) {
  constexpr int GS = 16;
  constexpr int EPL = COLS / GS;  // 8 (COLS=128) or 4 (COLS=64)
  constexpr int NU = EPL / 2;     // uints per lane: 4 or 2
  const int lane = threadIdx.x & 63;
  const int g = lane >> 4, l = lane & 15;
  const int C = (N + 3) / 4;
  const int c = blockIdx.x * 4 + (threadIdx.x >> 6);
  const int idx = g * C + c;
  const bool active = (c < C) && (idx < N);
  const int node = active ? perm[idx] : 0;

  float hi[EPL];
  {
    unsigned int tmp[NU];
    const unsigned short* hp = H + (size_t)node * COLS + l * EPL;
    if constexpr (NU == 4) *(uint4*)tmp = *(const uint4*)hp;
    else                   *(uint2*)tmp = *(const uint2*)hp;
#pragma unroll
    for (int u = 0; u < NU; ++u) { hi[2 * u] = bflo(tmp[u]); hi[2 * u + 1] = bfhi(tmp[u]); }
  }
  const float hri = hr[node];
  const int start = active ? rowptr[node] : 0;
  const int end = active ? rowptr[node + 1] : 0;

  float m = -INFINITY, sumw = 0.f;
  float acc[EPL];
#pragma unroll
  for (int j = 0; j < EPL; ++j) acc[j] = 0.f;

  unsigned int hvA[NU], hvB[NU];
  float hlA = 0.f, hlB = 0.f;
  int e = start;
  if (e < end) {
    int s = csr_src[e];
    hlA = hl[s];
    const unsigned short* hp = H + (size_t)s * COLS + l * EPL;
    if constexpr (NU == 4) *(uint4*)hvA = *(const uint4*)hp;
    else                   *(uint2*)hvA = *(const uint2*)hp;
  }
  if (e + 1 < end) {
    int s = csr_src[e + 1];
    hlB = hl[s];
    const unsigned short* hp = H + (size_t)s * COLS + l * EPL;
    if constexpr (NU == 4) *(uint4*)hvB = *(const uint4*)hp;
    else                   *(uint2*)hvB = *(const uint2*)hp;
  }
  int i2 = (e + 2 < end) ? csr_src[e + 2] : 0;
  int i3 = (e + 3 < end) ? csr_src[e + 3] : 0;

  auto COMPUTE = [&](const float* ch, float chl) {
    float d = 0.f;
#pragma unroll
    for (int j = 0; j < EPL; ++j) d = fmaf(hi[j], ch[j], d);
    d += __shfl_xor(d, 1);
    d += __shfl_xor(d, 2);
    d += __shfl_xor(d, 4);
    d += __shfl_xor(d, 8);
    float gate = 1.f / (1.f + __expf(-d));
    float a = (chl + hri) * gate;
    a = (a >= 0.f) ? a : 0.2f * a;
    float dm = a - m;
    if (dm > 30.f) {  // first edge (m=-inf) or rare big jump
      float sc = __expf(-dm);
      sumw *= sc;
#pragma unroll
      for (int j = 0; j < EPL; ++j) acc[j] *= sc;
      m = a;
      dm = 0.f;
    }
    float w = __expf(dm);  // bounded by e^30 - f32 safe
    sumw += w;
#pragma unroll
    for (int j = 0; j < EPL; ++j) acc[j] = fmaf(w, ch[j], acc[j]);
  };

  while (e + 1 < end) {
    float chA[EPL], chB[EPL];
#pragma unroll
    for (int u = 0; u < NU; ++u) { chA[2 * u] = bflo(hvA[u]); chA[2 * u + 1] = bfhi(hvA[u]); }
    float clA = hlA;
    if (e + 2 < end) {  // refill A (index i2 already resident)
      hlA = hl[i2];
      const unsigned short* hp = H + (size_t)i2 * COLS + l * EPL;
      if constexpr (NU == 4) *(uint4*)hvA = *(const uint4*)hp;
      else                   *(uint2*)hvA = *(const uint2*)hp;
    }
#pragma unroll
    for (int u = 0; u < NU; ++u) { chB[2 * u] = bflo(hvB[u]); chB[2 * u + 1] = bfhi(hvB[u]); }
    float clB = hlB;
    if (e + 3 < end) {  // refill B (index i3 already resident)
      hlB = hl[i3];
      const unsigned short* hp = H + (size_t)i3 * COLS + l * EPL;
      if constexpr (NU == 4) *(uint4*)hvB = *(const uint4*)hp;
      else                   *(uint2*)hvB = *(const uint2*)hp;
    }
    i2 = (e + 4 < end) ? csr_src[e + 4] : 0;
    i3 = (e + 5 < end) ? csr_src[e + 5] : 0;
    COMPUTE(chA, clA);
    COMPUTE(chB, clB);
    e += 2;
  }
  if (e < end) {
    float chA[EPL];
#pragma unroll
    for (int u = 0; u < NU; ++u) { chA[2 * u] = bflo(hvA[u]); chA[2 * u + 1] = bfhi(hvA[u]); }
    COMPUTE(chA, hlA);
  }

  if (active) {
    const float inv = 1.f / (sumw + 1e-16f);
    float o[EPL];
    const float* bp = b + l * EPL;
#pragma unroll
    for (int j = 0; j < EPL; ++j) o[j] = fmaxf(acc[j] * inv + bp[j], 0.f);

    if constexpr (LAST) {
      // COLS == 64, EPL == 4: log_softmax over the group's 64 values -> f32
      float* OUT = (float*)OUTv;
      float mx = o[0];
#pragma unroll
      for (int j = 1; j < EPL; ++j) mx = fmaxf(mx, o[j]);
      mx = fmaxf(mx, __shfl_xor(mx, 1));
      mx = fmaxf(mx, __shfl_xor(mx, 2));
      mx = fmaxf(mx, __shfl_xor(mx, 4));
      mx = fmaxf(mx, __shfl_xor(mx, 8));
      float es = 0.f;
#pragma unroll
      for (int j = 0; j < EPL; ++j) es += __expf(o[j] - mx);
      es += __shfl_xor(es, 1);
      es += __shfl_xor(es, 2);
      es += __shfl_xor(es, 4);
      es += __shfl_xor(es, 8);
      float ls = logf(es);
      float4 ov = make_float4(o[0] - mx - ls, o[1] - mx - ls,
                              o[2] - mx - ls, o[3] - mx - ls);
      *(float4*)(&OUT[(size_t)node * 64 + l * 4]) = ov;
    } else {
      // bf16 output (next layer's GEMM A operand), EPL == 8
      unsigned short* OUT = (unsigned short*)OUTv;
      unsigned int pk[NU];
#pragma unroll
      for (int u = 0; u < NU; ++u) pk[u] = f2bf_pack(o[2 * u], o[2 * u + 1]);
      *(uint4*)(OUT + (size_t)node * COLS + l * EPL) =
          make_uint4(pk[0], pk[1], pk[2], pk[3]);
    }
  }
}

// ---------------- launch ----------------
extern "C" void kernel_launch(void* const* d_in, const int* in_sizes, int n_in,
                              void* d_out, int out_size, void* d_ws, size_t ws_size,
                              hipStream_t stream) {
  const float* x = (const float*)d_in[0];
  const int* ei = (const int*)d_in[1];
  const float* W0 = (const float*)d_in[2];
  const float* al0 = (const float*)d_in[3];
  const float* ar0 = (const float*)d_in[4];
  const float* b0 = (const float*)d_in[5];
  const float* W1 = (const float*)d_in[6];
  const float* al1 = (const float*)d_in[7];
  const float* ar1 = (const float*)d_in[8];
  const float* b1 = (const float*)d_in[9];
  const float* W2 = (const float*)d_in[10];
  const float* al2 = (const float*)d_in[11];
  const float* ar2 = (const float*)d_in[12];
  const float* b2 = (const float*)d_in[13];

  const int N = in_sizes[0] / 128;  // 50000
  const int E = in_sizes[1] / 2;    // 640000
  const int ETOT = E + N;

  char* p = (char*)d_ws;
  auto carve = [&](size_t bytes) {
    void* r = (void*)p;
    p += (bytes + 255) & ~(size_t)255;
    return r;
  };
  unsigned short* Hb = (unsigned short*)carve((size_t)N * 128 * 2);  // bf16 GEMM out
  unsigned short* Ob = (unsigned short*)carve((size_t)N * 128 * 2);  // bf16 node out
  float* hl = (float*)carve((size_t)N * sizeof(float));
  float* hr = (float*)carve((size_t)N * sizeof(float));
  int* counts = (int*)carve((size_t)N * sizeof(int));
  int* excl = (int*)carve((size_t)N * sizeof(int));
  int* bsums = (int*)carve(1024 * sizeof(int));
  int* rowptr = (int*)carve((size_t)(N + 1) * sizeof(int));
  int* cursor = (int*)carve((size_t)(N + 1) * sizeof(int));
  int* csr_src = (int*)carve((size_t)ETOT * sizeof(int));
  int* dhist = (int*)carve(1024 * sizeof(int));
  int* perm = (int*)carve((size_t)N * sizeof(int));
  unsigned short* Wt0 = (unsigned short*)carve(128 * 136 * 2);
  unsigned short* Wt1 = (unsigned short*)carve(128 * 136 * 2);
  unsigned short* Wt2 = (unsigned short*)carve(64 * 136 * 2);

  const int nbs = (N + 255) / 256;        // 196
  const int nbe = (ETOT + 255) / 256;     // 2696

  // ---- preprocessing: 6 kernels ----
  prep0_kernel<<<nbs, 256, 0, stream>>>(W0, W1, W2, Wt0, Wt1, Wt2, counts, dhist, N);
  histo_kernel<<<nbe, 256, 0, stream>>>(ei, E, N, counts);
  scan1_deghist_kernel<<<nbs, 256, 0, stream>>>(counts, excl, bsums, dhist, N);
  scan2_degscan_kernel<<<2, 256, 0, stream>>>(bsums, nbs, dhist);
  scan3_kernel<<<(N + 256) / 256 + 1, 256, 0, stream>>>(excl, bsums, rowptr, cursor, N, ETOT);
  scatter_degscatter_kernel<<<nbe, 256, 0, stream>>>(ei, E, N, cursor, csr_src, rowptr,
                                                     dhist, perm);

  const int gemm_grid = (N + 63) / 64;
  const int C = (N + 3) / 4;
  const int node_grid = (C + 3) / 4;

  // layer 0: A = x (f32, cast in-flight)
  gemm_mfma<128, true><<<gemm_grid, 256, 0, stream>>>(x, Wt0, al0, ar0, Hb, hl, hr, N);
  node_kernel<128, false><<<node_grid, 256, 0, stream>>>(Hb, hl, hr, rowptr, csr_src, perm, b0, Ob, N);

  // layer 1: A = Ob (bf16)
  gemm_mfma<128, false><<<gemm_grid, 256, 0, stream>>>(Ob, Wt1, al1, ar1, Hb, hl, hr, N);
  node_kernel<128, false><<<node_grid, 256, 0, stream>>>(Hb, hl, hr, rowptr, csr_src, perm, b1, Ob, N);

  // layer 2: A = Ob (bf16), COLS = 64
  gemm_mfma<64, false><<<gemm_grid, 256, 0, stream>>>(Ob, Wt2, al2, ar2, Hb, hl, hr, N);
  node_kernel<64, true><<<node_grid, 256, 0, stream>>>(Hb, hl, hr, rowptr, csr_src, perm, b2,
                                                       d_out, N);
}